// Round 3
// baseline (66.437 us; speedup 1.0000x reference)
//
#include <hip/hip_runtime.h>
#include <hip/hip_bf16.h>

// Problem constants: B=64, T=1024, D=2, max_lag = T/4 = 256.
#define TT 1024
#define DD 2
#define MAXLAG 256
#define LAGCH 4              // 4 lag-chunks of 64 lags; grid = B x 4 = 256 blocks (1/CU)
#define BATCH 64

// Single fused kernel.
// Block (b,c): stages traj row b in LDS, computes msd for lags c*64+1..c*64+64
// (lane <-> lag, wave <-> p-stripe), folds them into 3 scalars
// (S1=sum resid*m, S2=sum resid^2*m, Sm=sum m), publishes via device-scope
// atomicExch. Last block (atomic counter) gathers 256x3 scalars via
// atomicAdd(p,0) coherent reads, computes per_traj per b and the mean.
// per_traj = (S2 - 2*I*S1 + I^2*Sm)/denom with I = S1/denom, denom=max(Sm,1),
// since sq_err = (intercept - resid)^2.
__global__ __launch_bounds__(256) void fused_kernel(const float* __restrict__ alpha_pred,
                                                    const float* __restrict__ traj,
                                                    const int* __restrict__ lengths,
                                                    float* __restrict__ out,
                                                    float* __restrict__ slots,      // [B*LAGCH*3]
                                                    unsigned* __restrict__ counter) {
    __shared__ float s[TT * DD];          // 8 KB trajectory row
    __shared__ float red[64 * 4];         // per-lag cross-wave partials
    __shared__ int winner;

    const int b = blockIdx.x;
    const int c = blockIdx.y;
    const int t = threadIdx.x;
    const int lane = t & 63;
    const int w = t >> 6;

    // Stage row b: 512 float4 loads over 256 threads (coalesced).
    const float4* t4 = (const float4*)(traj + (size_t)b * TT * DD);
    float4* s4 = (float4*)s;
    s4[t] = t4[t];
    s4[t + 256] = t4[t + 256];
    __syncthreads();

    const int L = lengths[b];
    const int lag = c * 64 + lane + 1;    // lane-consecutive lags
    const int cnt = L - lag;              // valid p in [0,cnt); cnt >= 256 here
    const float2* s2 = (const float2*)s;

    float acc = 0.0f;
    #pragma unroll 4
    for (int p = w; p < cnt; p += 4) {    // p wave-uniform -> s2[p] broadcast
        float2 a = s2[p];
        float2 e = s2[p + lag];           // lane-consecutive float2 (2-way, free)
        float dx = e.x - a.x;
        float dy = e.y - a.y;
        acc += dx * dx + dy * dy;
    }
    red[lane * 4 + w] = acc;
    __syncthreads();

    if (w == 0) {
        float4 r = ((const float4*)red)[lane];       // sum 4 p-stripes
        float sum = r.x + r.y + r.z + r.w;
        float mask = (L > lag) ? 1.0f : 0.0f;
        float cntf = fmaxf((float)cnt, 1.0f);
        float resid = logf(sum / cntf + 1e-8f) - alpha_pred[b] * logf((float)lag);
        float S1 = resid * mask;
        float S2 = resid * resid * mask;
        float Sm = mask;
        for (int off = 32; off; off >>= 1) {
            S1 += __shfl_down(S1, off, 64);
            S2 += __shfl_down(S2, off, 64);
            Sm += __shfl_down(Sm, off, 64);
        }
        if (lane == 0) {
            float* sl = slots + ((size_t)b * LAGCH + c) * 3;
            atomicExch(&sl[0], S1);   // device-scope RMW: coherent across XCDs
            atomicExch(&sl[1], S2);
            atomicExch(&sl[2], Sm);
        }
    }

    if (t == 0) {
        __threadfence();
        unsigned old = atomicAdd(counter, 1u);
        unsigned total = gridDim.x * gridDim.y;      // 256
        // ws is poisoned 0xAA each launch; accept 0-init too (no poison reliance).
        winner = (old == total - 1u) || (old == 0xAAAAAAAAu + total - 1u);
    }
    __syncthreads();
    if (!winner) return;

    __threadfence();
    if (t < BATCH) {                                  // wave 0: thread t <-> batch t
        float s1 = 0.f, s2v = 0.f, sm = 0.f;
        #pragma unroll
        for (int cc = 0; cc < LAGCH; ++cc) {
            float* sl = slots + ((size_t)t * LAGCH + cc) * 3;
            s1  += atomicAdd(&sl[0], 0.0f);           // coherent RMW reads
            s2v += atomicAdd(&sl[1], 0.0f);
            sm  += atomicAdd(&sl[2], 0.0f);
        }
        float denom = fmaxf(sm, 1.0f);
        float I = s1 / denom;
        float pt = (s2v - 2.0f * I * s1 + I * I * sm) / denom;
        for (int off = 32; off; off >>= 1) pt += __shfl_down(pt, off, 64);
        if (t == 0) out[0] = pt * (1.0f / (float)BATCH);
    }
}

extern "C" void kernel_launch(void* const* d_in, const int* in_sizes, int n_in,
                              void* d_out, int out_size, void* d_ws, size_t ws_size,
                              hipStream_t stream) {
    const float* alpha = (const float*)d_in[0];
    const float* traj  = (const float*)d_in[1];
    const int*   lens  = (const int*)d_in[2];
    float* out = (float*)d_out;

    const int B = in_sizes[0];           // 64

    unsigned* counter = (unsigned*)d_ws;
    float* slots = (float*)((char*)d_ws + 16);        // B*LAGCH*3 floats

    dim3 grid(B, LAGCH);
    fused_kernel<<<grid, 256, 0, stream>>>(alpha, traj, lens, out, slots, counter);
}